// Round 1
// baseline (84.741 us; speedup 1.0000x reference)
//
#include <hip/hip_runtime.h>

#define NROWS 512
#define BHALF 256
#define DIM   512
#define TILE  64
#define DCHUNK 128
#define NCHUNK 4
#define NN (NROWS * NROWS)

// ws layout (floats):
//   [0*NN .. 4*NN)  : L2 partials, one NxN buffer per d-chunk
//   [4*NN .. 8*NN)  : L1 partials, one NxN buffer per d-chunk
//   [8*NN]          : sum(L2)   (atomic, zeroed each launch)
//   [8*NN+1]        : sum(L1)

#define ACC(A, Bb, IV, JV)                                    \
    {                                                         \
        const float d_ = (IV) - (JV);                         \
        a2[A][Bb] = fmaf(d_, d_, a2[A][Bb]);                  \
        a1[A][Bb] += fabsf(d_);                               \
    }

#define STEP(DD)                                              \
    {                                                         \
        const float4 ivv = *(const float4*)&ai[DD][ty4];      \
        const float4 jvv = *(const float4*)&aj[DD][tx4];      \
        ACC(0, 0, ivv.x, jvv.x) ACC(0, 1, ivv.x, jvv.y)       \
        ACC(0, 2, ivv.x, jvv.z) ACC(0, 3, ivv.x, jvv.w)       \
        ACC(1, 0, ivv.y, jvv.x) ACC(1, 1, ivv.y, jvv.y)       \
        ACC(1, 2, ivv.y, jvv.z) ACC(1, 3, ivv.y, jvv.w)       \
        ACC(2, 0, ivv.z, jvv.x) ACC(2, 1, ivv.z, jvv.y)       \
        ACC(2, 2, ivv.z, jvv.z) ACC(2, 3, ivv.z, jvv.w)       \
        ACC(3, 0, ivv.w, jvv.x) ACC(3, 1, ivv.w, jvv.y)       \
        ACC(3, 2, ivv.w, jvv.z) ACC(3, 3, ivv.w, jvv.w)       \
    }

__global__ __launch_bounds__(256) void k_dist(const float* __restrict__ src,
                                              const float* __restrict__ tgt,
                                              float* __restrict__ ws)
{
    // Transposed tiles: [d][row] so ds_read_b128 fetches 4 rows at one d.
    __shared__ float ai[DCHUNK][TILE];   // 32 KB
    __shared__ float aj[DCHUNK][TILE];   // 32 KB

    const int tj = blockIdx.x;   // 0..7  (j tile)
    const int ti = blockIdx.y;   // 0..7  (i tile)
    const int dc = blockIdx.z;   // 0..3  (d chunk)
    const int t  = threadIdx.x;

    // ---- stage global -> LDS (transposed) ----
    {
        const int r  = t & 63;       // row within tile (lanes span rows -> 2-way LDS write, free)
        const int dg = t >> 6;       // 0..3 (wave id -> d-group)
        const int gi = ti * TILE + r;
        const int gj = tj * TILE + r;
        const float* prow_i = (gi < BHALF ? src + (size_t)gi * DIM
                                          : tgt + (size_t)(gi - BHALF) * DIM) + dc * DCHUNK;
        const float* prow_j = (gj < BHALF ? src + (size_t)gj * DIM
                                          : tgt + (size_t)(gj - BHALF) * DIM) + dc * DCHUNK;
#pragma unroll
        for (int k = 0; k < 8; ++k) {
            const int d4 = dg * 8 + k;            // 0..31
            const float4 vi = *(const float4*)(prow_i + d4 * 4);
            const float4 vj = *(const float4*)(prow_j + d4 * 4);
            ai[d4 * 4 + 0][r] = vi.x; ai[d4 * 4 + 1][r] = vi.y;
            ai[d4 * 4 + 2][r] = vi.z; ai[d4 * 4 + 3][r] = vi.w;
            aj[d4 * 4 + 0][r] = vj.x; aj[d4 * 4 + 1][r] = vj.y;
            aj[d4 * 4 + 2][r] = vj.z; aj[d4 * 4 + 3][r] = vj.w;
        }
    }
    __syncthreads();

    const int tx  = t & 15;      // j sub-tile
    const int ty  = t >> 4;      // i sub-tile
    const int tx4 = tx * 4;
    const int ty4 = ty * 4;

    float a2[4][4], a1[4][4];
#pragma unroll
    for (int a = 0; a < 4; ++a)
#pragma unroll
        for (int b = 0; b < 4; ++b) { a2[a][b] = 0.f; a1[a][b] = 0.f; }

#pragma unroll 2
    for (int d = 0; d < DCHUNK; d += 2) {
        STEP(d)
        STEP(d + 1)
    }

    // ---- store per-d-chunk partial distance tiles (plain stores) ----
    float* part2 = ws + (size_t)dc * NN;
    float* part1 = ws + (size_t)(NCHUNK + dc) * NN;
    const int gj0 = tj * TILE + tx4;
#pragma unroll
    for (int a = 0; a < 4; ++a) {
        const int gi = ti * TILE + ty4 + a;
        const float4 s2 = make_float4(a2[a][0], a2[a][1], a2[a][2], a2[a][3]);
        const float4 s1 = make_float4(a1[a][0], a1[a][1], a1[a][2], a1[a][3]);
        *(float4*)&part2[(size_t)gi * NROWS + gj0] = s2;
        *(float4*)&part1[(size_t)gi * NROWS + gj0] = s1;
    }

    // ---- block sums -> global atomic (for bandwidth) ----
    float s2 = 0.f, s1 = 0.f;
#pragma unroll
    for (int a = 0; a < 4; ++a)
#pragma unroll
        for (int b = 0; b < 4; ++b) { s2 += a2[a][b]; s1 += a1[a][b]; }
#pragma unroll
    for (int off = 32; off > 0; off >>= 1) {
        s2 += __shfl_down(s2, off);
        s1 += __shfl_down(s1, off);
    }
    __syncthreads();                    // tiles no longer needed: reuse ai as scratch
    float* red = &ai[0][0];
    const int wave = t >> 6;
    if ((t & 63) == 0) { red[wave * 2] = s2; red[wave * 2 + 1] = s1; }
    __syncthreads();
    if (t == 0) {
        const float t2 = red[0] + red[2] + red[4] + red[6];
        const float t1 = red[1] + red[3] + red[5] + red[7];
        atomicAdd(ws + 8 * NN, t2);
        atomicAdd(ws + 8 * NN + 1, t1);
    }
}

__global__ __launch_bounds__(256) void k_mmd(const float* __restrict__ ws,
                                             float* __restrict__ out)
{
    // bw = S/(N^2-N)/100 ; exp factor f_t = 1/(bw*10^t) = (N^2-N)*100/S * 0.1^t
    const float S2 = ws[8 * NN];
    const float S1 = ws[8 * NN + 1];
    const float r2 = 26163200.0f / S2;   // 512*511*100
    const float r1 = 26163200.0f / S1;

    float acc = 0.f;
    const int base = blockIdx.x * 1024 + threadIdx.x;
#pragma unroll
    for (int q = 0; q < 4; ++q) {
        const int idx = base + q * 256;
        const float l2 = ws[idx] + ws[NN + idx] + ws[2 * NN + idx] + ws[3 * NN + idx];
        const float l1 = ws[4 * NN + idx] + ws[5 * NN + idx] + ws[6 * NN + idx] + ws[7 * NN + idx];
        float kv = 0.f;
        float f2 = r2, f1 = r1;
#pragma unroll
        for (int tt = 0; tt < 5; ++tt) {
            kv += __expf(-l2 * f2) + __expf(-l1 * f1);
            f2 *= 0.1f;
            f1 *= 0.1f;
        }
        const int i = idx >> 9;
        const int j = idx & 511;
        const float sgn = (((i ^ j) & BHALF) == 0) ? 1.0f : -1.0f;
        acc += sgn * kv;
    }
#pragma unroll
    for (int off = 32; off > 0; off >>= 1) acc += __shfl_down(acc, off);

    __shared__ float red[4];
    if ((threadIdx.x & 63) == 0) red[threadIdx.x >> 6] = acc;
    __syncthreads();
    if (threadIdx.x == 0) {
        const float s = red[0] + red[1] + red[2] + red[3];
        atomicAdd(out, s * (1.0f / 65536.0f));
    }
}

extern "C" void kernel_launch(void* const* d_in, const int* in_sizes, int n_in,
                              void* d_out, int out_size, void* d_ws, size_t ws_size,
                              hipStream_t stream)
{
    const float* src = (const float*)d_in[0];
    const float* tgt = (const float*)d_in[1];
    float* ws  = (float*)d_ws;
    float* out = (float*)d_out;

    // zero the atomic accumulators (sums + output)
    hipMemsetAsync(ws + 8 * NN, 0, 2 * sizeof(float), stream);
    hipMemsetAsync(out, 0, sizeof(float), stream);

    dim3 g1(8, 8, 4);
    k_dist<<<g1, 256, 0, stream>>>(src, tgt, ws);
    k_mmd<<<256, 256, 0, stream>>>(ws, out);
}

// Round 2
// 83.228 us; speedup vs baseline: 1.0182x; 1.0182x over previous
//
#include <hip/hip_runtime.h>

#define NROWS 512
#define BHALF 256
#define DIM   512
#define TILE  64
#define DCHUNK 64
#define NCHUNK 8
#define NN (NROWS * NROWS)
#define SOFF (16 * NN)          // block-sum partials: [SOFF, SOFF+512) = S2, [SOFF+512, SOFF+1024) = S1

// ws layout (floats):
//   [ 0*NN .. 8*NN)  : L2 partials, one NxN buffer per d-chunk (8 chunks of 64 dims)
//   [ 8*NN ..16*NN)  : L1 partials
//   [SOFF .. SOFF+1024) : per-block distance-sum partials (plain stores, no memset needed)

#define ACC(A, Bb, IV, JV)                                    \
    {                                                         \
        const float d_ = (IV) - (JV);                         \
        a2[A][Bb] = fmaf(d_, d_, a2[A][Bb]);                  \
        a1[A][Bb] += fabsf(d_);                               \
    }

#define STEP(DD)                                              \
    {                                                         \
        const float4 ivv = *(const float4*)&ai[DD][ty4];      \
        const float4 jvv = *(const float4*)&aj[DD][tx4];      \
        ACC(0, 0, ivv.x, jvv.x) ACC(0, 1, ivv.x, jvv.y)       \
        ACC(0, 2, ivv.x, jvv.z) ACC(0, 3, ivv.x, jvv.w)       \
        ACC(1, 0, ivv.y, jvv.x) ACC(1, 1, ivv.y, jvv.y)       \
        ACC(1, 2, ivv.y, jvv.z) ACC(1, 3, ivv.y, jvv.w)       \
        ACC(2, 0, ivv.z, jvv.x) ACC(2, 1, ivv.z, jvv.y)       \
        ACC(2, 2, ivv.z, jvv.z) ACC(2, 3, ivv.z, jvv.w)       \
        ACC(3, 0, ivv.w, jvv.x) ACC(3, 1, ivv.w, jvv.y)       \
        ACC(3, 2, ivv.w, jvv.z) ACC(3, 3, ivv.w, jvv.w)       \
    }

__global__ __launch_bounds__(256) void k_dist(const float* __restrict__ src,
                                              const float* __restrict__ tgt,
                                              float* __restrict__ ws)
{
    // Transposed tiles [d][row]: one ds_read_b128 fetches 4 rows at one d.
    // 32 KB total -> 2 blocks/CU (grid-limited) = 8 waves/CU for latency hiding.
    __shared__ float ai[DCHUNK][TILE];   // 16 KB
    __shared__ float aj[DCHUNK][TILE];   // 16 KB

    const int tj = blockIdx.x;   // 0..7  (j tile)
    const int ti = blockIdx.y;   // 0..7  (i tile)
    const int dc = blockIdx.z;   // 0..7  (d chunk of 64)
    const int t  = threadIdx.x;

    // ---- stage global -> LDS (transposed; writes are 2-way bank aliased = free) ----
    {
        const int r  = t & 63;       // row within tile
        const int dg = t >> 6;       // 0..3 (wave id -> d-group)
        const int gi = ti * TILE + r;
        const int gj = tj * TILE + r;
        const float* prow_i = (gi < BHALF ? src + (size_t)gi * DIM
                                          : tgt + (size_t)(gi - BHALF) * DIM) + dc * DCHUNK;
        const float* prow_j = (gj < BHALF ? src + (size_t)gj * DIM
                                          : tgt + (size_t)(gj - BHALF) * DIM) + dc * DCHUNK;
#pragma unroll
        for (int k = 0; k < 4; ++k) {
            const int d4 = dg * 4 + k;            // 0..15 float4-groups
            const float4 vi = *(const float4*)(prow_i + d4 * 4);
            const float4 vj = *(const float4*)(prow_j + d4 * 4);
            ai[d4 * 4 + 0][r] = vi.x; ai[d4 * 4 + 1][r] = vi.y;
            ai[d4 * 4 + 2][r] = vi.z; ai[d4 * 4 + 3][r] = vi.w;
            aj[d4 * 4 + 0][r] = vj.x; aj[d4 * 4 + 1][r] = vj.y;
            aj[d4 * 4 + 2][r] = vj.z; aj[d4 * 4 + 3][r] = vj.w;
        }
    }
    __syncthreads();

    const int tx  = t & 15;      // j sub-tile
    const int ty  = t >> 4;      // i sub-tile
    const int tx4 = tx * 4;
    const int ty4 = ty * 4;

    float a2[4][4], a1[4][4];
#pragma unroll
    for (int a = 0; a < 4; ++a)
#pragma unroll
        for (int b = 0; b < 4; ++b) { a2[a][b] = 0.f; a1[a][b] = 0.f; }

#pragma unroll 4
    for (int d = 0; d < DCHUNK; d += 2) {
        STEP(d)
        STEP(d + 1)
    }

    // ---- store per-d-chunk partial distance tiles (plain coalesced stores) ----
    float* part2 = ws + (size_t)dc * NN;
    float* part1 = ws + (size_t)(NCHUNK + dc) * NN;
    const int gj0 = tj * TILE + tx4;
#pragma unroll
    for (int a = 0; a < 4; ++a) {
        const int gi = ti * TILE + ty4 + a;
        const float4 s2 = make_float4(a2[a][0], a2[a][1], a2[a][2], a2[a][3]);
        const float4 s1 = make_float4(a1[a][0], a1[a][1], a1[a][2], a1[a][3]);
        *(float4*)&part2[(size_t)gi * NROWS + gj0] = s2;
        *(float4*)&part1[(size_t)gi * NROWS + gj0] = s1;
    }

    // ---- block distance-sums -> dedicated slots (no atomics, no memset) ----
    float s2 = 0.f, s1 = 0.f;
#pragma unroll
    for (int a = 0; a < 4; ++a)
#pragma unroll
        for (int b = 0; b < 4; ++b) { s2 += a2[a][b]; s1 += a1[a][b]; }
#pragma unroll
    for (int off = 32; off > 0; off >>= 1) {
        s2 += __shfl_down(s2, off);
        s1 += __shfl_down(s1, off);
    }
    __syncthreads();                    // tiles done: reuse ai as reduction scratch
    float* red = &ai[0][0];
    const int wave = t >> 6;
    if ((t & 63) == 0) { red[wave * 2] = s2; red[wave * 2 + 1] = s1; }
    __syncthreads();
    if (t == 0) {
        const int bid = (dc * 8 + ti) * 8 + tj;   // 0..511
        ws[SOFF + bid]       = red[0] + red[2] + red[4] + red[6];
        ws[SOFF + 512 + bid] = red[1] + red[3] + red[5] + red[7];
    }
}

__global__ __launch_bounds__(256) void k_mmd(const float* __restrict__ ws,
                                             float* __restrict__ out)
{
    const int t = threadIdx.x;
    __shared__ float sred[8];

    // ---- reduce the 512+512 block partials to S2, S1 (L2-hot, ~0.5 us) ----
    float sp2 = ws[SOFF + t] + ws[SOFF + 256 + t];
    float sp1 = ws[SOFF + 512 + t] + ws[SOFF + 768 + t];
#pragma unroll
    for (int off = 32; off > 0; off >>= 1) {
        sp2 += __shfl_down(sp2, off);
        sp1 += __shfl_down(sp1, off);
    }
    if ((t & 63) == 0) { sred[(t >> 6) * 2] = sp2; sred[(t >> 6) * 2 + 1] = sp1; }
    __syncthreads();
    const float S2 = sred[0] + sred[2] + sred[4] + sred[6];
    const float S1 = sred[1] + sred[3] + sred[5] + sred[7];
    // bw = S/(N^2-N)/100 ; factor_t = (N^2-N)*100/S * 0.1^t
    const float r2 = 26163200.0f / S2;   // 512*511*100
    const float r1 = 26163200.0f / S1;

    float acc = 0.f;
    const int base = blockIdx.x * 1024 + t;
#pragma unroll
    for (int q = 0; q < 4; ++q) {
        const int idx = base + q * 256;
        float l2 = 0.f, l1 = 0.f;
#pragma unroll
        for (int c = 0; c < NCHUNK; ++c) {
            l2 += ws[(size_t)c * NN + idx];
            l1 += ws[(size_t)(NCHUNK + c) * NN + idx];
        }
        float kv = 0.f;
        float f2 = r2, f1 = r1;
#pragma unroll
        for (int tt = 0; tt < 5; ++tt) {
            kv += __expf(-l2 * f2) + __expf(-l1 * f1);
            f2 *= 0.1f;
            f1 *= 0.1f;
        }
        const int i = idx >> 9;
        const int j = idx & 511;
        const float sgn = (((i ^ j) & BHALF) == 0) ? 1.0f : -1.0f;
        acc += sgn * kv;
    }
#pragma unroll
    for (int off = 32; off > 0; off >>= 1) acc += __shfl_down(acc, off);

    __syncthreads();
    if ((t & 63) == 0) sred[t >> 6] = acc;
    __syncthreads();
    if (t == 0) {
        const float s = sred[0] + sred[1] + sred[2] + sred[3];
        atomicAdd(out, s * (1.0f / 65536.0f));
    }
}

extern "C" void kernel_launch(void* const* d_in, const int* in_sizes, int n_in,
                              void* d_out, int out_size, void* d_ws, size_t ws_size,
                              hipStream_t stream)
{
    const float* src = (const float*)d_in[0];
    const float* tgt = (const float*)d_in[1];
    float* ws  = (float*)d_ws;
    float* out = (float*)d_out;

    hipMemsetAsync(out, 0, sizeof(float), stream);   // only remaining zero-init

    dim3 g1(8, 8, 8);
    k_dist<<<g1, 256, 0, stream>>>(src, tgt, ws);
    k_mmd<<<256, 256, 0, stream>>>(ws, out);
}

// Round 3
// 78.821 us; speedup vs baseline: 1.0751x; 1.0559x over previous
//
#include <hip/hip_runtime.h>
#include <hip/hip_fp16.h>

#define NROWS 512
#define BHALF 256
#define DIM   512
#define TILE  64
#define DCHUNK 64
#define NCHUNK 8
#define NN (NROWS * NROWS)
#define SOFF (8 * NN)   // float offset of per-block distance-sum partials
// ws layout:
//   bytes [0 .. 8*NN*4)        : packed half2(l2_partial, l1_partial), one NN-buffer per d-chunk
//   floats [SOFF .. SOFF+1024) : per-block sum partials (512 S2, then 512 S1)

#define ACC(A, Bb, IV, JV)                                    \
    {                                                         \
        const float d_ = (IV) - (JV);                         \
        a2[A][Bb] = fmaf(d_, d_, a2[A][Bb]);                  \
        a1[A][Bb] += fabsf(d_);                               \
    }

#define STEP(DD)                                              \
    {                                                         \
        const float4 ivv = *(const float4*)&ai[DD][ty4];      \
        const float4 jvv = *(const float4*)&aj[DD][tx4];      \
        ACC(0, 0, ivv.x, jvv.x) ACC(0, 1, ivv.x, jvv.y)       \
        ACC(0, 2, ivv.x, jvv.z) ACC(0, 3, ivv.x, jvv.w)       \
        ACC(1, 0, ivv.y, jvv.x) ACC(1, 1, ivv.y, jvv.y)       \
        ACC(1, 2, ivv.y, jvv.z) ACC(1, 3, ivv.y, jvv.w)       \
        ACC(2, 0, ivv.z, jvv.x) ACC(2, 1, ivv.z, jvv.y)       \
        ACC(2, 2, ivv.z, jvv.z) ACC(2, 3, ivv.z, jvv.w)       \
        ACC(3, 0, ivv.w, jvv.x) ACC(3, 1, ivv.w, jvv.y)       \
        ACC(3, 2, ivv.w, jvv.z) ACC(3, 3, ivv.w, jvv.w)       \
    }

__device__ __forceinline__ unsigned int pack_h2(float l2v, float l1v) {
    const __half2 h = __halves2half2(__float2half_rn(l2v), __float2half_rn(l1v));
    union { __half2 h; unsigned int u; } c; c.h = h;
    return c.u;
}

__global__ __launch_bounds__(256) void k_dist(const float* __restrict__ src,
                                              const float* __restrict__ tgt,
                                              float* __restrict__ ws,
                                              float* __restrict__ out)
{
    __shared__ float ai[DCHUNK][TILE];   // 16 KB, transposed [d][row]
    __shared__ float aj[DCHUNK][TILE];   // 16 KB

    const int tj = blockIdx.x;   // 0..7
    const int ti = blockIdx.y;   // 0..7
    const int dc = blockIdx.z;   // 0..7
    const int t  = threadIdx.x;

    // fold the out-zeroing into this kernel (stream order: before k_mmd's atomics)
    if (t == 0 && tj == 0 && ti == 0 && dc == 0) out[0] = 0.0f;

    // ---- stage global -> LDS (transposed; 2-way bank aliasing = free) ----
    {
        const int r  = t & 63;
        const int dg = t >> 6;
        const int gi = ti * TILE + r;
        const int gj = tj * TILE + r;
        const float* prow_i = (gi < BHALF ? src + (size_t)gi * DIM
                                          : tgt + (size_t)(gi - BHALF) * DIM) + dc * DCHUNK;
        const float* prow_j = (gj < BHALF ? src + (size_t)gj * DIM
                                          : tgt + (size_t)(gj - BHALF) * DIM) + dc * DCHUNK;
#pragma unroll
        for (int k = 0; k < 4; ++k) {
            const int d4 = dg * 4 + k;
            const float4 vi = *(const float4*)(prow_i + d4 * 4);
            const float4 vj = *(const float4*)(prow_j + d4 * 4);
            ai[d4 * 4 + 0][r] = vi.x; ai[d4 * 4 + 1][r] = vi.y;
            ai[d4 * 4 + 2][r] = vi.z; ai[d4 * 4 + 3][r] = vi.w;
            aj[d4 * 4 + 0][r] = vj.x; aj[d4 * 4 + 1][r] = vj.y;
            aj[d4 * 4 + 2][r] = vj.z; aj[d4 * 4 + 3][r] = vj.w;
        }
    }
    __syncthreads();

    const int tx  = t & 15;
    const int ty  = t >> 4;
    const int tx4 = tx * 4;
    const int ty4 = ty * 4;

    float a2[4][4], a1[4][4];
#pragma unroll
    for (int a = 0; a < 4; ++a)
#pragma unroll
        for (int b = 0; b < 4; ++b) { a2[a][b] = 0.f; a1[a][b] = 0.f; }

#pragma unroll 4
    for (int d = 0; d < DCHUNK; d += 2) {
        STEP(d)
        STEP(d + 1)
    }

    // ---- store packed half2(l2,l1) partial tiles: 4B/pair -> 8 MB total ----
    unsigned int* part = (unsigned int*)ws + (size_t)dc * NN;
    const int gj0 = tj * TILE + tx4;
#pragma unroll
    for (int a = 0; a < 4; ++a) {
        const int gi = ti * TILE + ty4 + a;
        const uint4 pk = make_uint4(pack_h2(a2[a][0], a1[a][0]),
                                    pack_h2(a2[a][1], a1[a][1]),
                                    pack_h2(a2[a][2], a1[a][2]),
                                    pack_h2(a2[a][3], a1[a][3]));
        *(uint4*)&part[(size_t)gi * NROWS + gj0] = pk;
    }

    // ---- block distance-sums (exact fp32) -> dedicated slots ----
    float s2 = 0.f, s1 = 0.f;
#pragma unroll
    for (int a = 0; a < 4; ++a)
#pragma unroll
        for (int b = 0; b < 4; ++b) { s2 += a2[a][b]; s1 += a1[a][b]; }
#pragma unroll
    for (int off = 32; off > 0; off >>= 1) {
        s2 += __shfl_down(s2, off);
        s1 += __shfl_down(s1, off);
    }
    __syncthreads();
    float* red = &ai[0][0];
    const int wave = t >> 6;
    if ((t & 63) == 0) { red[wave * 2] = s2; red[wave * 2 + 1] = s1; }
    __syncthreads();
    if (t == 0) {
        const int bid = (dc * 8 + ti) * 8 + tj;
        ws[SOFF + bid]       = red[0] + red[2] + red[4] + red[6];
        ws[SOFF + 512 + bid] = red[1] + red[3] + red[5] + red[7];
    }
}

__global__ __launch_bounds__(256) void k_mmd(const float* __restrict__ ws,
                                             float* __restrict__ out)
{
    const int t = threadIdx.x;
    __shared__ float sred[8];

    // ---- reduce 512+512 block partials to S2, S1 ----
    float sp2 = ws[SOFF + t] + ws[SOFF + 256 + t];
    float sp1 = ws[SOFF + 512 + t] + ws[SOFF + 768 + t];
#pragma unroll
    for (int off = 32; off > 0; off >>= 1) {
        sp2 += __shfl_down(sp2, off);
        sp1 += __shfl_down(sp1, off);
    }
    if ((t & 63) == 0) { sred[(t >> 6) * 2] = sp2; sred[(t >> 6) * 2 + 1] = sp1; }
    __syncthreads();
    const float S2 = sred[0] + sred[2] + sred[4] + sred[6];
    const float S1 = sred[1] + sred[3] + sred[5] + sred[7];
    // bw = S/(N^2-N)/100 ; factor_t = (N^2-N)*100/S * 0.1^t
    const float r2 = 26163200.0f / S2;   // 512*511*100
    const float r1 = 26163200.0f / S1;

    const __half2* part = (const __half2*)ws;

    float acc = 0.f;
    const int base = blockIdx.x * 1024 + t;
#pragma unroll
    for (int q = 0; q < 4; ++q) {
        const int idx = base + q * 256;
        float l2 = 0.f, l1 = 0.f;
#pragma unroll
        for (int c = 0; c < NCHUNK; ++c) {
            const float2 f = __half22float2(part[(size_t)c * NN + idx]);
            l2 += f.x;
            l1 += f.y;
        }
        float kv = 0.f;
        float f2 = r2, f1 = r1;
#pragma unroll
        for (int tt = 0; tt < 5; ++tt) {
            kv += __expf(-l2 * f2) + __expf(-l1 * f1);
            f2 *= 0.1f;
            f1 *= 0.1f;
        }
        const int i = idx >> 9;
        const int j = idx & 511;
        const float sgn = (((i ^ j) & BHALF) == 0) ? 1.0f : -1.0f;
        acc += sgn * kv;
    }
#pragma unroll
    for (int off = 32; off > 0; off >>= 1) acc += __shfl_down(acc, off);

    __syncthreads();
    if ((t & 63) == 0) sred[t >> 6] = acc;
    __syncthreads();
    if (t == 0) {
        const float s = sred[0] + sred[1] + sred[2] + sred[3];
        atomicAdd(out, s * (1.0f / 65536.0f));
    }
}

extern "C" void kernel_launch(void* const* d_in, const int* in_sizes, int n_in,
                              void* d_out, int out_size, void* d_ws, size_t ws_size,
                              hipStream_t stream)
{
    const float* src = (const float*)d_in[0];
    const float* tgt = (const float*)d_in[1];
    float* ws  = (float*)d_ws;
    float* out = (float*)d_out;

    dim3 g1(8, 8, 8);
    k_dist<<<g1, 256, 0, stream>>>(src, tgt, ws, out);
    k_mmd<<<256, 256, 0, stream>>>(ws, out);
}